// Round 7
// baseline (352.863 us; speedup 1.0000x reference)
//
#include <hip/hip_runtime.h>
#include <hip/hip_bf16.h>

// ---------------- types ----------------
typedef __bf16 bf16x8 __attribute__((ext_vector_type(8)));
typedef float  f32x4  __attribute__((ext_vector_type(4)));

#define GM 16384
#define GN 2048
#define GK 3072        // logical K: hi*hi + hi*lo + lo*hi
#define PK 2048        // physical packed width: [hi | lo]
#define DIM 1024
#define NSPLIT 1023
#define NLEAF 1024
#define NTILES 48      // logical K-tiles of 64

// ---------------- helpers ----------------
__device__ __forceinline__ void gload_lds16(const void* g, void* lds) {
    __builtin_amdgcn_global_load_lds(
        (const __attribute__((address_space(1))) void*)g,
        (__attribute__((address_space(3))) void*)lds, 16, 0, 0);
}

// ---------------- merged pack kernel ----------------
// blocks 0..8191: A' = [hi(1024)|lo(1024)] per row of x  (GM x PK)
// blocks 8192..9215: B' rows 0-1022 W_split, 1023-2046 W_leaf, 2047 zeros
__global__ void pack_kernel(const float* __restrict__ x,
                            const float* __restrict__ Ws,
                            const float* __restrict__ Wl,
                            __bf16* __restrict__ Ap,
                            __bf16* __restrict__ Bp) {
    int bid = blockIdx.x;
    float vs[8];
    __bf16* base;
    if (bid < 8192) {
        size_t tid = (size_t)bid * 256 + threadIdx.x;
        size_t idx = tid * 8;
        int m = (int)(idx >> 10);
        int k = (int)(idx & 1023);
        float4 v0 = *(const float4*)(x + idx);
        float4 v1 = *(const float4*)(x + idx + 4);
        vs[0]=v0.x; vs[1]=v0.y; vs[2]=v0.z; vs[3]=v0.w;
        vs[4]=v1.x; vs[5]=v1.y; vs[6]=v1.z; vs[7]=v1.w;
        base = Ap + (size_t)m * PK + k;
    } else {
        size_t tid = (size_t)(bid - 8192) * 256 + threadIdx.x;
        size_t idx = tid * 8;
        int n = (int)(idx >> 10);
        int k = (int)(idx & 1023);
        if (n < NSPLIT) {
            const float* s = Ws + (size_t)n * DIM + k;
            float4 v0 = *(const float4*)(s);
            float4 v1 = *(const float4*)(s + 4);
            vs[0]=v0.x; vs[1]=v0.y; vs[2]=v0.z; vs[3]=v0.w;
            vs[4]=v1.x; vs[5]=v1.y; vs[6]=v1.z; vs[7]=v1.w;
        } else if (n < NSPLIT + NLEAF) {
            const float* s = Wl + (size_t)(n - NSPLIT) * DIM + k;
            float4 v0 = *(const float4*)(s);
            float4 v1 = *(const float4*)(s + 4);
            vs[0]=v0.x; vs[1]=v0.y; vs[2]=v0.z; vs[3]=v0.w;
            vs[4]=v1.x; vs[5]=v1.y; vs[6]=v1.z; vs[7]=v1.w;
        } else {
#pragma unroll
            for (int j = 0; j < 8; ++j) vs[j] = 0.0f;
        }
        base = Bp + (size_t)n * PK + k;
    }
    bf16x8 hi, lo;
#pragma unroll
    for (int j = 0; j < 8; ++j) {
        __bf16 h = (__bf16)vs[j];
        hi[j] = h;
        lo[j] = (__bf16)(vs[j] - (float)h);
    }
    *(bf16x8*)(base)        = hi;
    *(bf16x8*)(base + 1024) = lo;
}

// ---------------- GEMM: round-1 structure (proven 203 us) + dedup pack ----
// 128x128 tile, BK=64, 256 threads (4 waves, 2x2), mfma 16x16x32 bf16.
// LDS linear dest for global_load_lds; XOR swizzle (kc ^= row&7) applied on
// the GLOBAL source side and again on the ds_read side (involution).
// Logical K-tiles map into the [hi|lo] packed layout via KOA/KOB:
//   A: t0-15 hi, t16-31 hi again, t32-47 lo;  B: t0-15 hi, t16-31 lo, t32-47 hi
// giving  sum = hi*hi + hi*lo + lo*hi.
__global__ __launch_bounds__(256, 2) void gemm_kernel(const __bf16* __restrict__ A,
                                                      const __bf16* __restrict__ B,
                                                      const float* __restrict__ bs,
                                                      const float* __restrict__ bl,
                                                      float* __restrict__ C) {
    __shared__ __bf16 As[128 * 64];
    __shared__ __bf16 Bs[128 * 64];

    const int t    = threadIdx.x;
    const int wave = t >> 6;
    const int lane = t & 63;
    const int wr   = wave >> 1;   // 0..1
    const int wc   = wave & 1;    // 0..1

    // XCD-chunked swizzle: 2048 blocks = 8 xcds * 256; consecutive tiles in a
    // chunk share mt (nt-fastest) so the A-panel (512 KiB) stays L2-resident.
    int g    = blockIdx.x;
    int tile = (g & 7) * 256 + (g >> 3);
    int mt   = tile >> 4;         // 0..127
    int nt   = tile & 15;         // 0..15

    const __bf16* Abase = A + (size_t)mt * 128 * PK;
    const __bf16* Bbase = B + (size_t)nt * 128 * PK;

    // staging coords: chunk c = i*256 + t; r = c>>3 (8 chunks/row), col swz
    int rS[4], cS[4];
#pragma unroll
    for (int i = 0; i < 4; ++i) {
        int c  = i * 256 + t;
        rS[i]  = c >> 3;
        cS[i]  = (c & 7) ^ (rS[i] & 7);
    }

#define KOA(T) (((T) < 32) ? (T) * 64 : (T) * 64 - 1024)
#define KOB(T) (((T) < 32) ? (T) * 64 : (T) * 64 - 2048)

    f32x4 acc[4][4];
#pragma unroll
    for (int i = 0; i < 4; ++i)
#pragma unroll
        for (int j = 0; j < 4; ++j) acc[i][j] = (f32x4){0.f, 0.f, 0.f, 0.f};

    for (int tt = 0; tt < NTILES; ++tt) {
        const int kA = KOA(tt);
        const int kB = KOB(tt);
        __syncthreads();
#pragma unroll
        for (int i = 0; i < 4; ++i)
            gload_lds16(Abase + (size_t)rS[i] * PK + kA + cS[i] * 8,
                        &As[(i * 256 + wave * 64) * 8]);
#pragma unroll
        for (int i = 0; i < 4; ++i)
            gload_lds16(Bbase + (size_t)rS[i] * PK + kB + cS[i] * 8,
                        &Bs[(i * 256 + wave * 64) * 8]);
        __syncthreads();   // compiler emits s_waitcnt vmcnt(0) before barrier

#pragma unroll
        for (int ks = 0; ks < 2; ++ks) {
            bf16x8 af[4], bfr[4];
#pragma unroll
            for (int m = 0; m < 4; ++m) {
                int row = wr * 64 + m * 16 + (lane & 15);
                int kc  = ks * 4 + (lane >> 4);
                af[m] = *(const bf16x8*)&As[row * 64 + ((kc ^ (row & 7)) * 8)];
            }
#pragma unroll
            for (int n = 0; n < 4; ++n) {
                int row = wc * 64 + n * 16 + (lane & 15);
                int kc  = ks * 4 + (lane >> 4);
                bfr[n] = *(const bf16x8*)&Bs[row * 64 + ((kc ^ (row & 7)) * 8)];
            }
#pragma unroll
            for (int m = 0; m < 4; ++m)
#pragma unroll
                for (int n = 0; n < 4; ++n)
                    acc[m][n] = __builtin_amdgcn_mfma_f32_16x16x32_bf16(
                        af[m], bfr[n], acc[m][n], 0, 0, 0);
        }
    }
#undef KOA
#undef KOB

    // epilogue: fused bias + sigmoid (split cols) / bias (leaf cols)
    const int r0 = mt * 128 + wr * 64 + (lane >> 4) * 4;
    const int c0 = nt * 128 + wc * 64 + (lane & 15);
#pragma unroll
    for (int m = 0; m < 4; ++m)
#pragma unroll
        for (int n = 0; n < 4; ++n) {
            int col = c0 + n * 16;
#pragma unroll
            for (int j = 0; j < 4; ++j) {
                float v = acc[m][n][j];
                float o;
                if (col < NSPLIT) {
                    v += bs[col];
                    o = 1.0f / (1.0f + __expf(-v));
                } else if (col < NSPLIT + NLEAF) {
                    o = v + bl[col - NSPLIT];
                } else {
                    o = 0.0f;
                }
                C[(size_t)(r0 + m * 16 + j) * GN + col] = o;
            }
        }
}

// ---------------- routing: pure product walk (proven rounds 3-6) ----------
__global__ __launch_bounds__(256) void routing_kernel(const float* __restrict__ S,
                                                      float* __restrict__ out) {
    __shared__ float rowbuf[4][2048];
    const int wave = threadIdx.x >> 6;
    const int lane = threadIdx.x & 63;
    const int b    = blockIdx.x * 4 + wave;

    const float* srow = S + (size_t)b * GN;
#pragma unroll
    for (int i = 0; i < 8; ++i) {
        int idx = i * 64 + lane;
        *(float4*)&rowbuf[wave][idx * 4] = ((const float4*)srow)[idx];
    }
    __syncthreads();

    float acc = 0.0f;
#pragma unroll
    for (int j = 0; j < 16; ++j) {
        int l = j * 64 + lane;
        float w = 1.0f;
        int off = 0;
#pragma unroll
        for (int d = 0; d < 10; ++d) {
            int node = off + (l >> (10 - d));
            float p  = rowbuf[wave][node];
            int bit  = (l >> (9 - d)) & 1;
            w *= bit ? p : (1.0f - p);
            off += (1 << d);
        }
        acc += w * rowbuf[wave][NSPLIT + l];
    }
#pragma unroll
    for (int s = 32; s > 0; s >>= 1) acc += __shfl_down(acc, s, 64);
    if (lane == 0) out[b] = acc;
}

// ---------------- launcher ----------------
extern "C" void kernel_launch(void* const* d_in, const int* in_sizes, int n_in,
                              void* d_out, int out_size, void* d_ws, size_t ws_size,
                              hipStream_t stream) {
    const float* x      = (const float*)d_in[0];
    const float* Wsplit = (const float*)d_in[1];
    const float* bsplit = (const float*)d_in[2];
    const float* Wleaf  = (const float*)d_in[3];
    const float* bleaf  = (const float*)d_in[4];
    float* out          = (float*)d_out;

    char* ws = (char*)d_ws;
    __bf16* Ap = (__bf16*)ws;                                   // 64 MiB
    __bf16* Bp = (__bf16*)(ws + (size_t)GM * PK * 2);           // 8 MiB
    float*  S  = (float*)(ws + (size_t)GM * PK * 2 + (size_t)GN * PK * 2); // 128 MiB

    // A: 8192 blocks, B: 1024 blocks
    pack_kernel<<<9216, 256, 0, stream>>>(x, Wsplit, Wleaf, Ap, Bp);

    // 128 mt x 16 nt = 2048 blocks of 256 threads
    gemm_kernel<<<2048, 256, 0, stream>>>(Ap, Bp, bsplit, bleaf, S);

    routing_kernel<<<GM / 4, 256, 0, stream>>>(S, out);
}

// Round 11
// 350.541 us; speedup vs baseline: 1.0066x; 1.0066x over previous
//
#include <hip/hip_runtime.h>
#include <hip/hip_bf16.h>

// ---------------- types ----------------
typedef __bf16 bf16x8 __attribute__((ext_vector_type(8)));
typedef float  f32x4  __attribute__((ext_vector_type(4)));

#define GM 16384
#define GN 2048
#define DIM 1024
#define NSPLIT 1023
#define NLEAF 1024
#define PKP 2176       // padded row stride (elems): 4352 B, breaks 4 KiB channel aliasing
#define NKCH 16        // K-chunks of 64

// ---------------- helpers ----------------
__device__ __forceinline__ void gload_lds16(const void* g, void* lds) {
    __builtin_amdgcn_global_load_lds(
        (const __attribute__((address_space(1))) void*)g,
        (__attribute__((address_space(3))) void*)lds, 16, 0, 0);
}

// ---------------- merged pack kernel ----------------
// blocks 0..8191: A' row m of x -> [hi(1024) | lo(1024)] at stride PKP
// blocks 8192..9215: B' rows 0-1022 W_split, 1023-2046 W_leaf, 2047 zeros
__global__ void pack_kernel(const float* __restrict__ x,
                            const float* __restrict__ Ws,
                            const float* __restrict__ Wl,
                            __bf16* __restrict__ Ap,
                            __bf16* __restrict__ Bp) {
    int bid = blockIdx.x;
    float vs[8];
    __bf16* base;
    if (bid < 8192) {
        size_t tid = (size_t)bid * 256 + threadIdx.x;
        size_t idx = tid * 8;
        int m = (int)(idx >> 10);
        int k = (int)(idx & 1023);
        float4 v0 = *(const float4*)(x + idx);
        float4 v1 = *(const float4*)(x + idx + 4);
        vs[0]=v0.x; vs[1]=v0.y; vs[2]=v0.z; vs[3]=v0.w;
        vs[4]=v1.x; vs[5]=v1.y; vs[6]=v1.z; vs[7]=v1.w;
        base = Ap + (size_t)m * PKP + k;
    } else {
        size_t tid = (size_t)(bid - 8192) * 256 + threadIdx.x;
        size_t idx = tid * 8;
        int n = (int)(idx >> 10);
        int k = (int)(idx & 1023);
        if (n < NSPLIT) {
            const float* s = Ws + (size_t)n * DIM + k;
            float4 v0 = *(const float4*)(s);
            float4 v1 = *(const float4*)(s + 4);
            vs[0]=v0.x; vs[1]=v0.y; vs[2]=v0.z; vs[3]=v0.w;
            vs[4]=v1.x; vs[5]=v1.y; vs[6]=v1.z; vs[7]=v1.w;
        } else if (n < NSPLIT + NLEAF) {
            const float* s = Wl + (size_t)(n - NSPLIT) * DIM + k;
            float4 v0 = *(const float4*)(s);
            float4 v1 = *(const float4*)(s + 4);
            vs[0]=v0.x; vs[1]=v0.y; vs[2]=v0.z; vs[3]=v0.w;
            vs[4]=v1.x; vs[5]=v1.y; vs[6]=v1.z; vs[7]=v1.w;
        } else {
#pragma unroll
            for (int j = 0; j < 8; ++j) vs[j] = 0.0f;
        }
        base = Bp + (size_t)n * PKP + k;
    }
    bf16x8 hi, lo;
#pragma unroll
    for (int j = 0; j < 8; ++j) {
        __bf16 h = (__bf16)vs[j];
        hi[j] = h;
        lo[j] = (__bf16)(vs[j] - (float)h);
    }
    *(bf16x8*)(base)        = hi;
    *(bf16x8*)(base + 1024) = lo;
}

// ---------------- GEMM: 128x128 tile, 3-pass K-chunk loop --------------
// Per K-chunk kk (k in [kk*64, kk*64+64)):
//   pass1 = A_hi.B_hi, pass2 = A_hi.B_lo, pass3 = A_lo.B_hi
// A_hi/B_hi staged once and consumed by two passes (regs persist), so A-hi
// HBM traffic and staging instructions drop ~33% vs the 3x-logical-K walk.
// Each stage overlaps 32-64 MFMA issued right after it (loads in flight
// until the next __syncthreads drains vmcnt).
// Swizzle (proven, 0 conflicts): LDS chunk j of row R holds global chunk
// j^(R&7); reads use kc^(R&7). 4 barriers / 96 MFMA per chunk.
__global__ __launch_bounds__(256, 2) void gemm_kernel(const __bf16* __restrict__ A,
                                                      const __bf16* __restrict__ B,
                                                      const float* __restrict__ bs,
                                                      const float* __restrict__ bl,
                                                      float* __restrict__ C) {
    __shared__ __bf16 As[128 * 64];
    __shared__ __bf16 Bs[128 * 64];

    const int t    = threadIdx.x;
    const int wave = t >> 6;
    const int lane = t & 63;
    const int wr   = wave >> 1;   // 0..1
    const int wc   = wave & 1;    // 0..1
    const int r15  = lane & 15;
    const int c4   = lane >> 4;   // 0..3

    // XCD-chunked swizzle: 2048 blocks = 8 xcds * 256, nt-fastest in chunk
    int g    = blockIdx.x;
    int tile = (g & 7) * 256 + (g >> 3);
    int mt   = tile >> 4;         // 0..127
    int nt   = tile & 15;         // 0..15

    const __bf16* Abase = A + (size_t)mt * 128 * PKP;
    const __bf16* Bbase = B + (size_t)nt * 128 * PKP;

    // staging: tile = 128 rows x 8 chunks of 16B; chunk c = i*256 + t
    const __bf16* gA[4];
    const __bf16* gB[4];
#pragma unroll
    for (int i = 0; i < 4; ++i) {
        int c  = i * 256 + t;
        int r  = c >> 3;
        int cs = (c & 7) ^ (r & 7);
        gA[i] = Abase + (size_t)r * PKP + cs * 8;
        gB[i] = Bbase + (size_t)r * PKP + cs * 8;
    }

#define STAGE_AB(koff) do {                                              \
        _Pragma("unroll")                                                \
        for (int i_ = 0; i_ < 4; ++i_)                                   \
            gload_lds16(gA[i_] + (koff), &As[(i_ * 256 + wave * 64) * 8]);\
        _Pragma("unroll")                                                \
        for (int i_ = 0; i_ < 4; ++i_)                                   \
            gload_lds16(gB[i_] + (koff), &Bs[(i_ * 256 + wave * 64) * 8]);\
    } while (0)

#define RD_FRAGS(af, bf)  do {                                           \
        _Pragma("unroll")                                                \
        for (int ks_ = 0; ks_ < 2; ++ks_) {                              \
            _Pragma("unroll")                                            \
            for (int m_ = 0; m_ < 4; ++m_) {                             \
                int row_ = wr * 64 + m_ * 16 + r15;                      \
                int kc_  = ks_ * 4 + c4;                                 \
                af[ks_][m_] = *(const bf16x8*)&As[row_ * 64 + ((kc_ ^ (row_ & 7)) * 8)]; \
            }                                                            \
            _Pragma("unroll")                                            \
            for (int n_ = 0; n_ < 4; ++n_) {                             \
                int row_ = wc * 64 + n_ * 16 + r15;                      \
                int kc_  = ks_ * 4 + c4;                                 \
                bf[ks_][n_] = *(const bf16x8*)&Bs[row_ * 64 + ((kc_ ^ (row_ & 7)) * 8)]; \
            }                                                            \
        }                                                                \
    } while (0)

#define PASS(af, bf) do {                                                \
        _Pragma("unroll")                                                \
        for (int ks_ = 0; ks_ < 2; ++ks_)                                \
            _Pragma("unroll")                                            \
            for (int m_ = 0; m_ < 4; ++m_)                               \
                _Pragma("unroll")                                        \
                for (int n_ = 0; n_ < 4; ++n_)                           \
                    acc[m_][n_] = __builtin_amdgcn_mfma_f32_16x16x32_bf16(\
                        af[ks_][m_], bf[ks_][n_], acc[m_][n_], 0, 0, 0); \
    } while (0)

    f32x4 acc[4][4];
#pragma unroll
    for (int i = 0; i < 4; ++i)
#pragma unroll
        for (int j = 0; j < 4; ++j) acc[i][j] = (f32x4){0.f, 0.f, 0.f, 0.f};

    // prologue: stage hi(0)
    STAGE_AB(0);

    for (int kk = 0; kk < NKCH; ++kk) {
        const int kl = 1024 + kk * 64;           // lo offset this chunk
        __syncthreads();                         // hi(kk) landed (vmcnt drain)
        bf16x8 afh[2][4], bfh[2][4];
        RD_FRAGS(afh, bfh);
        __syncthreads();                         // all waves consumed hi
        STAGE_AB(kl);                            // stage lo, overlaps pass1
        PASS(afh, bfh);                          // pass1: hi.hi
        __syncthreads();                         // lo landed (vmcnt drain)
        bf16x8 afl[2][4], bfl[2][4];
        RD_FRAGS(afl, bfl);
        __syncthreads();                         // all waves consumed lo
        if (kk < NKCH - 1) STAGE_AB((kk + 1) * 64);  // next hi, overlaps pass2+3
        PASS(afh, bfl);                          // pass2: hi.lo
        PASS(afl, bfh);                          // pass3: lo.hi
    }
#undef STAGE_AB
#undef RD_FRAGS
#undef PASS

    // epilogue: fused bias + sigmoid (split cols) / bias (leaf cols)
    const int r0 = mt * 128 + wr * 64 + (lane >> 4) * 4;
    const int c0 = nt * 128 + wc * 64 + r15;
#pragma unroll
    for (int m = 0; m < 4; ++m)
#pragma unroll
        for (int n = 0; n < 4; ++n) {
            int col = c0 + n * 16;
#pragma unroll
            for (int j = 0; j < 4; ++j) {
                float v = acc[m][n][j];
                float o;
                if (col < NSPLIT) {
                    v += bs[col];
                    o = 1.0f / (1.0f + __expf(-v));
                } else if (col < NSPLIT + NLEAF) {
                    o = v + bl[col - NSPLIT];
                } else {
                    o = 0.0f;
                }
                C[(size_t)(r0 + m * 16 + j) * GN + col] = o;
            }
        }
}

// ---------------- routing: pure product walk (proven rounds 3-7) ----------
__global__ __launch_bounds__(256) void routing_kernel(const float* __restrict__ S,
                                                      float* __restrict__ out) {
    __shared__ float rowbuf[4][2048];
    const int wave = threadIdx.x >> 6;
    const int lane = threadIdx.x & 63;
    const int b    = blockIdx.x * 4 + wave;

    const float* srow = S + (size_t)b * GN;
#pragma unroll
    for (int i = 0; i < 8; ++i) {
        int idx = i * 64 + lane;
        *(float4*)&rowbuf[wave][idx * 4] = ((const float4*)srow)[idx];
    }
    __syncthreads();

    float acc = 0.0f;
#pragma unroll
    for (int j = 0; j < 16; ++j) {
        int l = j * 64 + lane;
        float w = 1.0f;
        int off = 0;
#pragma unroll
        for (int d = 0; d < 10; ++d) {
            int node = off + (l >> (10 - d));
            float p  = rowbuf[wave][node];
            int bit  = (l >> (9 - d)) & 1;
            w *= bit ? p : (1.0f - p);
            off += (1 << d);
        }
        acc += w * rowbuf[wave][NSPLIT + l];
    }
#pragma unroll
    for (int s = 32; s > 0; s >>= 1) acc += __shfl_down(acc, s, 64);
    if (lane == 0) out[b] = acc;
}

// ---------------- launcher ----------------
extern "C" void kernel_launch(void* const* d_in, const int* in_sizes, int n_in,
                              void* d_out, int out_size, void* d_ws, size_t ws_size,
                              hipStream_t stream) {
    const float* x      = (const float*)d_in[0];
    const float* Wsplit = (const float*)d_in[1];
    const float* bsplit = (const float*)d_in[2];
    const float* Wleaf  = (const float*)d_in[3];
    const float* bleaf  = (const float*)d_in[4];
    float* out          = (float*)d_out;

    char* ws = (char*)d_ws;
    __bf16* Ap = (__bf16*)ws;                                    // GM*PKP*2 = 68 MiB
    __bf16* Bp = (__bf16*)(ws + (size_t)GM * PKP * 2);           // GN*PKP*2 = 8.5 MiB
    float*  S  = (float*)(ws + (size_t)GM * PKP * 2 + (size_t)GN * PKP * 2); // 128 MiB

    // A: 8192 blocks, B: 1024 blocks
    pack_kernel<<<9216, 256, 0, stream>>>(x, Wsplit, Wleaf, Ap, Bp);

    // 128 mt x 16 nt = 2048 blocks of 256 threads
    gemm_kernel<<<2048, 256, 0, stream>>>(Ap, Bp, bsplit, bleaf, S);

    routing_kernel<<<GM / 4, 256, 0, stream>>>(S, out);
}

// Round 12
// 222.465 us; speedup vs baseline: 1.5862x; 1.5757x over previous
//
#include <hip/hip_runtime.h>
#include <hip/hip_bf16.h>

// ---------------- types ----------------
typedef _Float16 f16x8 __attribute__((ext_vector_type(8)));
typedef float    f32x4 __attribute__((ext_vector_type(4)));

#define GM 16384
#define GN 2048
#define DIM 1024
#define NSPLIT 1023
#define NLEAF 1024
#define PKF 1088       // padded fp16 row stride (elems): 2176 B, breaks 2 KiB aliasing
#define NKT 16         // K-tiles of 64 (K = 1024, single product)

// ---------------- helpers ----------------
__device__ __forceinline__ void gload_lds16(const void* g, void* lds) {
    __builtin_amdgcn_global_load_lds(
        (const __attribute__((address_space(1))) void*)g,
        (__attribute__((address_space(3))) void*)lds, 16, 0, 0);
}

// ---------------- merged pack kernel: f32 -> f16, padded stride ----------
// blocks 0..8191: A' row m of x (GM x DIM -> stride PKF)
// blocks 8192..9215: B' rows 0-1022 W_split, 1023-2046 W_leaf, 2047 zeros
__global__ void pack_kernel(const float* __restrict__ x,
                            const float* __restrict__ Ws,
                            const float* __restrict__ Wl,
                            _Float16* __restrict__ Ap,
                            _Float16* __restrict__ Bp) {
    int bid = blockIdx.x;
    float vs[8];
    _Float16* base;
    if (bid < 8192) {
        size_t tid = (size_t)bid * 256 + threadIdx.x;
        size_t idx = tid * 8;
        int m = (int)(idx >> 10);
        int k = (int)(idx & 1023);
        float4 v0 = *(const float4*)(x + idx);
        float4 v1 = *(const float4*)(x + idx + 4);
        vs[0]=v0.x; vs[1]=v0.y; vs[2]=v0.z; vs[3]=v0.w;
        vs[4]=v1.x; vs[5]=v1.y; vs[6]=v1.z; vs[7]=v1.w;
        base = Ap + (size_t)m * PKF + k;
    } else {
        size_t tid = (size_t)(bid - 8192) * 256 + threadIdx.x;
        size_t idx = tid * 8;
        int n = (int)(idx >> 10);
        int k = (int)(idx & 1023);
        if (n < NSPLIT) {
            const float* s = Ws + (size_t)n * DIM + k;
            float4 v0 = *(const float4*)(s);
            float4 v1 = *(const float4*)(s + 4);
            vs[0]=v0.x; vs[1]=v0.y; vs[2]=v0.z; vs[3]=v0.w;
            vs[4]=v1.x; vs[5]=v1.y; vs[6]=v1.z; vs[7]=v1.w;
        } else if (n < NSPLIT + NLEAF) {
            const float* s = Wl + (size_t)(n - NSPLIT) * DIM + k;
            float4 v0 = *(const float4*)(s);
            float4 v1 = *(const float4*)(s + 4);
            vs[0]=v0.x; vs[1]=v0.y; vs[2]=v0.z; vs[3]=v0.w;
            vs[4]=v1.x; vs[5]=v1.y; vs[6]=v1.z; vs[7]=v1.w;
        } else {
#pragma unroll
            for (int j = 0; j < 8; ++j) vs[j] = 0.0f;
        }
        base = Bp + (size_t)n * PKF + k;
    }
    f16x8 h;
#pragma unroll
    for (int j = 0; j < 8; ++j) h[j] = (_Float16)vs[j];
    *(f16x8*)(base) = h;
}

// ---------------- GEMM: r1-proven 128x128 2-barrier structure, fp16 K=1024
// 256 threads (4 waves, 2x2), per-wave 64x64 (4x4 frags of 16x16x32 f16).
// Rationale (r1/r3/r4/r6/r11 measured): simple 2-barrier loop at ~3
// blocks/CU beats every deeper pipeline tried (inter-block overlap, m114).
// Swizzle (measured 0 conflicts): LDS chunk j of row R holds global chunk
// j^(R&7); reads use kc^(R&7) (both-sides involution).
__global__ __launch_bounds__(256, 2) void gemm_kernel(const _Float16* __restrict__ A,
                                                      const _Float16* __restrict__ B,
                                                      const float* __restrict__ bs,
                                                      const float* __restrict__ bl,
                                                      float* __restrict__ C) {
    __shared__ _Float16 As[128 * 64];
    __shared__ _Float16 Bs[128 * 64];

    const int t    = threadIdx.x;
    const int wave = t >> 6;
    const int lane = t & 63;
    const int wr   = wave >> 1;   // 0..1
    const int wc   = wave & 1;    // 0..1
    const int r15  = lane & 15;
    const int c4   = lane >> 4;   // 0..3

    // XCD-chunked swizzle: 2048 blocks = 8 xcds * 256, nt-fastest in chunk
    int g    = blockIdx.x;
    int tile = (g & 7) * 256 + (g >> 3);
    int mt   = tile >> 4;         // 0..127
    int nt   = tile & 15;         // 0..15

    const _Float16* Abase = A + (size_t)mt * 128 * PKF;
    const _Float16* Bbase = B + (size_t)nt * 128 * PKF;

    // staging: K-tile = 128 rows x 8 chunks of 16B; chunk c = i*256 + t
    const _Float16* gA[4];
    const _Float16* gB[4];
#pragma unroll
    for (int i = 0; i < 4; ++i) {
        int c  = i * 256 + t;
        int r  = c >> 3;
        int cs = (c & 7) ^ (r & 7);
        gA[i] = Abase + (size_t)r * PKF + cs * 8;
        gB[i] = Bbase + (size_t)r * PKF + cs * 8;
    }

    f32x4 acc[4][4];
#pragma unroll
    for (int i = 0; i < 4; ++i)
#pragma unroll
        for (int j = 0; j < 4; ++j) acc[i][j] = (f32x4){0.f, 0.f, 0.f, 0.f};

    for (int tt = 0; tt < NKT; ++tt) {
        const int k0 = tt * 64;
        __syncthreads();                 // previous reads done before overwrite
#pragma unroll
        for (int i = 0; i < 4; ++i)
            gload_lds16(gA[i] + k0, &As[(i * 256 + wave * 64) * 8]);
#pragma unroll
        for (int i = 0; i < 4; ++i)
            gload_lds16(gB[i] + k0, &Bs[(i * 256 + wave * 64) * 8]);
        __syncthreads();                 // vmcnt(0) drain: tile landed

#pragma unroll
        for (int ks = 0; ks < 2; ++ks) {
            f16x8 af[4], bfr[4];
#pragma unroll
            for (int m = 0; m < 4; ++m) {
                int row = wr * 64 + m * 16 + r15;
                int kc  = ks * 4 + c4;
                af[m] = *(const f16x8*)&As[row * 64 + ((kc ^ (row & 7)) * 8)];
            }
#pragma unroll
            for (int n = 0; n < 4; ++n) {
                int row = wc * 64 + n * 16 + r15;
                int kc  = ks * 4 + c4;
                bfr[n] = *(const f16x8*)&Bs[row * 64 + ((kc ^ (row & 7)) * 8)];
            }
#pragma unroll
            for (int m = 0; m < 4; ++m)
#pragma unroll
                for (int n = 0; n < 4; ++n)
                    acc[m][n] = __builtin_amdgcn_mfma_f32_16x16x32_f16(
                        af[m], bfr[n], acc[m][n], 0, 0, 0);
        }
    }

    // epilogue: fused bias + sigmoid (split cols) / bias (leaf cols)
    const int r0 = mt * 128 + wr * 64 + (lane >> 4) * 4;
    const int c0 = nt * 128 + wc * 64 + r15;
#pragma unroll
    for (int m = 0; m < 4; ++m)
#pragma unroll
        for (int n = 0; n < 4; ++n) {
            int col = c0 + n * 16;
#pragma unroll
            for (int j = 0; j < 4; ++j) {
                float v = acc[m][n][j];
                float o;
                if (col < NSPLIT) {
                    v += bs[col];
                    o = 1.0f / (1.0f + __expf(-v));
                } else if (col < NSPLIT + NLEAF) {
                    o = v + bl[col - NSPLIT];
                } else {
                    o = 0.0f;
                }
                C[(size_t)(r0 + m * 16 + j) * GN + col] = o;
            }
        }
}

// ---------------- routing: pure product walk (proven rounds 3-11) ---------
__global__ __launch_bounds__(256) void routing_kernel(const float* __restrict__ S,
                                                      float* __restrict__ out) {
    __shared__ float rowbuf[4][2048];
    const int wave = threadIdx.x >> 6;
    const int lane = threadIdx.x & 63;
    const int b    = blockIdx.x * 4 + wave;

    const float* srow = S + (size_t)b * GN;
#pragma unroll
    for (int i = 0; i < 8; ++i) {
        int idx = i * 64 + lane;
        *(float4*)&rowbuf[wave][idx * 4] = ((const float4*)srow)[idx];
    }
    __syncthreads();

    float acc = 0.0f;
#pragma unroll
    for (int j = 0; j < 16; ++j) {
        int l = j * 64 + lane;
        float w = 1.0f;
        int off = 0;
#pragma unroll
        for (int d = 0; d < 10; ++d) {
            int node = off + (l >> (10 - d));
            float p  = rowbuf[wave][node];
            int bit  = (l >> (9 - d)) & 1;
            w *= bit ? p : (1.0f - p);
            off += (1 << d);
        }
        acc += w * rowbuf[wave][NSPLIT + l];
    }
#pragma unroll
    for (int s = 32; s > 0; s >>= 1) acc += __shfl_down(acc, s, 64);
    if (lane == 0) out[b] = acc;
}

// ---------------- launcher ----------------
extern "C" void kernel_launch(void* const* d_in, const int* in_sizes, int n_in,
                              void* d_out, int out_size, void* d_ws, size_t ws_size,
                              hipStream_t stream) {
    const float* x      = (const float*)d_in[0];
    const float* Wsplit = (const float*)d_in[1];
    const float* bsplit = (const float*)d_in[2];
    const float* Wleaf  = (const float*)d_in[3];
    const float* bleaf  = (const float*)d_in[4];
    float* out          = (float*)d_out;

    char* ws = (char*)d_ws;
    _Float16* Ap = (_Float16*)ws;                                  // GM*PKF*2 = 34 MiB
    _Float16* Bp = (_Float16*)(ws + (size_t)GM * PKF * 2);         // GN*PKF*2 = 4.25 MiB
    float*    S  = (float*)(ws + (size_t)GM * PKF * 2 + (size_t)GN * PKF * 2); // 128 MiB

    // A: 8192 blocks, B: 1024 blocks
    pack_kernel<<<9216, 256, 0, stream>>>(x, Wsplit, Wleaf, Ap, Bp);

    // 128 mt x 16 nt = 2048 blocks of 256 threads
    gemm_kernel<<<2048, 256, 0, stream>>>(Ap, Bp, bsplit, bleaf, S);

    routing_kernel<<<GM / 4, 256, 0, stream>>>(S, out);
}